// Round 3
// baseline (2388.278 us; speedup 1.0000x reference)
//
#include <hip/hip_runtime.h>
#include <float.h>

// Problem constants: B=2, N=4096, K=20, H=384
// Inputs: fp32 arrays (values bf16-quantized by harness). Output: fp32.
#define NPTS_B 4096
#define NPTS 8192            // B*N
#define KNN 20
#define NSAMP (NPTS*KNN)     // 163840

// -------- bf16 helpers for INTERNAL staging only --------
static __device__ __forceinline__ float bf2f(unsigned short u) {
  return __uint_as_float(((unsigned int)u) << 16);
}
static __device__ __forceinline__ unsigned short f2bf(float f) {
  unsigned int u = __float_as_uint(f);
  u += 0x7fffu + ((u >> 16) & 1u);
  return (unsigned short)(u >> 16);
}

// ============================================================
// K1: KNN (one block per point). d2 = sq_i + sq_j - 2*dot, fp contract off
// (inputs are bf16-grid -> products exact in fp32 -> matches np reference).
// Selection: 20 rounds of lex-min (d2, j) == top_k stable tie-break.
// Also writes xyz passthrough output (exact fp32 copy).
// ============================================================
__global__ __launch_bounds__(256) void knn_kernel(const float* __restrict__ xyz,
                                                  int* __restrict__ idx,
                                                  float* __restrict__ out_xyz) {
#pragma clang fp contract(off)
  int p = blockIdx.x;            // 0..8191
  int base = p & ~4095;          // batch base row
  int tid = threadIdx.x;
  const float* xb = xyz + (size_t)base * 3;
  float xi0 = xyz[p*3+0], xi1 = xyz[p*3+1], xi2 = xyz[p*3+2];
  float sqi = (xi0*xi0 + xi1*xi1) + xi2*xi2;
  float dist[16];
#pragma unroll
  for (int u = 0; u < 16; ++u) {
    int j = tid + (u << 8);
    float a0 = xb[j*3+0], a1 = xb[j*3+1], a2 = xb[j*3+2];
    float sqj = (a0*a0 + a1*a1) + a2*a2;
    float dt  = (xi0*a0 + xi1*a1) + xi2*a2;
    dist[u] = (sqi + sqj) - 2.0f*dt;
  }
  __shared__ float wd[4];
  __shared__ int   wj[4];
  __shared__ int   win_j;
  for (int r = 0; r < 20; ++r) {
    float bd = dist[0]; int bj = tid;
#pragma unroll
    for (int u = 1; u < 16; ++u) {
      int j = tid + (u << 8);
      if (dist[u] < bd || (dist[u] == bd && j < bj)) { bd = dist[u]; bj = j; }
    }
#pragma unroll
    for (int off = 32; off; off >>= 1) {
      float od = __shfl_down(bd, off);
      int   oj = __shfl_down(bj, off);
      if (od < bd || (od == bd && oj < bj)) { bd = od; bj = oj; }
    }
    if ((tid & 63) == 0) { wd[tid >> 6] = bd; wj[tid >> 6] = bj; }
    __syncthreads();
    if (tid == 0) {
      float d0 = wd[0]; int j0 = wj[0];
#pragma unroll
      for (int w = 1; w < 4; ++w)
        if (wd[w] < d0 || (wd[w] == d0 && wj[w] < j0)) { d0 = wd[w]; j0 = wj[w]; }
      win_j = j0;
      idx[p*20 + r] = base + j0;   // store GLOBAL row index
    }
    __syncthreads();
    int jw = win_j;
    int slot = jw >> 8;
    if ((jw & 255) == tid) {
#pragma unroll
      for (int u = 0; u < 16; ++u) if (u == slot) dist[u] = FLT_MAX;
    }
  }
  if (tid < 3) out_xyz[p*3 + tid] = xyz[p*3 + tid];   // exact fp32 copy
}

// ============================================================
// K2: BN1 statistics — recompute h1 = e@W1 + b1 per sample,
// accumulate per-channel sum / sumsq into 32 buckets.
// ============================================================
__global__ __launch_bounds__(256) void h1_stats_kernel(const float* __restrict__ xyz,
                                                       const int* __restrict__ idx,
                                                       const float* __restrict__ W1,
                                                       const float* __restrict__ b1,
                                                       float* __restrict__ s1buck) {
  int blk = blockIdx.x;         // 320 blocks * 512 samples
  int tid = threadIdx.x;
  int c = tid & 127, half = tid >> 7;
  float w[6];
#pragma unroll
  for (int d = 0; d < 6; ++d) w[d] = W1[d*128 + c];
  float bb = b1[c];
  float sum = 0.f, sq = 0.f;
  int s0 = blk * 512;
  for (int u = 0; u < 256; ++u) {
    int s = s0 + (u << 1) + half;
    unsigned int p = (unsigned int)s / 20u;
    int jg = idx[s];
    float xi0 = xyz[p*3+0], xi1 = xyz[p*3+1], xi2 = xyz[p*3+2];
    float e0 = xyz[jg*3+0] - xi0;
    float e1 = xyz[jg*3+1] - xi1;
    float e2 = xyz[jg*3+2] - xi2;
    float h = bb;
    h = fmaf(e0, w[0], h); h = fmaf(e1, w[1], h); h = fmaf(e2, w[2], h);
    h = fmaf(xi0, w[3], h); h = fmaf(xi1, w[4], h); h = fmaf(xi2, w[5], h);
    sum += h; sq = fmaf(h, h, sq);
  }
  __shared__ float ls[128], lq[128];
  if (!half) { ls[c] = sum; lq[c] = sq; }
  __syncthreads();
  if (half) {
    int bkt = (blk & 31) * 256;
    atomicAdd(&s1buck[bkt + c], ls[c] + sum);
    atomicAdd(&s1buck[bkt + 128 + c], lq[c] + sq);
  }
}

__global__ void bn_prep1(const float* __restrict__ g1, const float* __restrict__ be1,
                         const float* __restrict__ s1buck, float* __restrict__ misc) {
  int c = threadIdx.x;  // 128
  float s = 0.f, q = 0.f;
  for (int b = 0; b < 32; ++b) { s += s1buck[b*256 + c]; q += s1buck[b*256 + 128 + c]; }
  const float inv = 1.0f / (float)NSAMP;
  float mu = s * inv;
  float var = q * inv - mu * mu;
  float a = g1[c] / sqrtf(var + 1e-5f);
  misc[c] = a;
  misc[128 + c] = be1[c] - mu * a;
}

// ============================================================
// K4: per point: edge -> h1 (BN1+ReLU) -> h2 (128->256) -> gmax over K.
// Writes h2 and gmax as bf16 staging. Block = point, thread = h2 channel.
// ============================================================
__global__ __launch_bounds__(256) void h2_kernel(const float* __restrict__ xyz,
                                                 const int* __restrict__ idx,
                                                 const float* __restrict__ W1,
                                                 const float* __restrict__ b1,
                                                 const float* __restrict__ W2,
                                                 const float* __restrict__ b2,
                                                 const float* __restrict__ misc,
                                                 unsigned short* __restrict__ h2out,
                                                 unsigned short* __restrict__ gmaxout) {
  int p = blockIdx.x;
  int tid = threadIdx.x;
  __shared__ float e[20][6];
  __shared__ float h1t[128*20];  // [c][n]
  if (tid < 20) {
    int jg = idx[p*20 + tid];
    float xi0 = xyz[p*3+0], xi1 = xyz[p*3+1], xi2 = xyz[p*3+2];
    e[tid][0] = xyz[jg*3+0] - xi0;
    e[tid][1] = xyz[jg*3+1] - xi1;
    e[tid][2] = xyz[jg*3+2] - xi2;
    e[tid][3] = xi0; e[tid][4] = xi1; e[tid][5] = xi2;
  }
  __syncthreads();
#pragma unroll
  for (int u = 0; u < 10; ++u) {
    int id = tid + (u << 8);           // 0..2559 = 128c * 20n
    int c = (unsigned int)id / 20u;
    int n = id - c * 20;
    float v = b1[c];
#pragma unroll
    for (int d = 0; d < 6; ++d) v = fmaf(e[n][d], W1[d*128 + c], v);
    v = fmaxf(fmaf(misc[c], v, misc[128 + c]), 0.f);
    h1t[c*20 + n] = v;
  }
  __syncthreads();
  int c = tid;
  float acc[20];
  float bb = b2[c];
#pragma unroll
  for (int n = 0; n < 20; ++n) acc[n] = bb;
  const float* w2c = W2 + c;
#pragma unroll 2
  for (int k = 0; k < 128; ++k) {
    float w = w2c[k*256];
    const float4* hp = (const float4*)&h1t[k*20];
    float4 h0 = hp[0], h1v = hp[1], h2v = hp[2], h3v = hp[3], h4v = hp[4];
    acc[0]  = fmaf(h0.x, w, acc[0]);  acc[1]  = fmaf(h0.y, w, acc[1]);
    acc[2]  = fmaf(h0.z, w, acc[2]);  acc[3]  = fmaf(h0.w, w, acc[3]);
    acc[4]  = fmaf(h1v.x, w, acc[4]); acc[5]  = fmaf(h1v.y, w, acc[5]);
    acc[6]  = fmaf(h1v.z, w, acc[6]); acc[7]  = fmaf(h1v.w, w, acc[7]);
    acc[8]  = fmaf(h2v.x, w, acc[8]); acc[9]  = fmaf(h2v.y, w, acc[9]);
    acc[10] = fmaf(h2v.z, w, acc[10]); acc[11] = fmaf(h2v.w, w, acc[11]);
    acc[12] = fmaf(h3v.x, w, acc[12]); acc[13] = fmaf(h3v.y, w, acc[13]);
    acc[14] = fmaf(h3v.z, w, acc[14]); acc[15] = fmaf(h3v.w, w, acc[15]);
    acc[16] = fmaf(h4v.x, w, acc[16]); acc[17] = fmaf(h4v.y, w, acc[17]);
    acc[18] = fmaf(h4v.z, w, acc[18]); acc[19] = fmaf(h4v.w, w, acc[19]);
  }
  float g = acc[0];
#pragma unroll
  for (int n = 1; n < 20; ++n) g = fmaxf(g, acc[n]);
  gmaxout[(size_t)p*256 + c] = f2bf(g);
#pragma unroll
  for (int n = 0; n < 20; ++n)
    h2out[(size_t)(p*20 + n)*256 + c] = f2bf(acc[n]);
}

// ============================================================
// K5: h3 = [gmax | h2] @ W3 + b3  (163840x512 @ 512x512), fp32 vector FMA.
// Tile 128M x 64N, micro 8x4. Fused BN3-stat partials (bucketed atomics).
// ============================================================
__global__ __launch_bounds__(256) void gemm3_kernel(const unsigned short* __restrict__ h2,
                                                    const unsigned short* __restrict__ gmax,
                                                    const float* __restrict__ W3,
                                                    const float* __restrict__ b3,
                                                    unsigned short* __restrict__ h3,
                                                    float* __restrict__ s3buck) {
  int bid = blockIdx.x;               // 1280 * 8
  int bn = bid & 7, bm = bid >> 3;
  int m0 = bm << 7, n0 = bn << 6;
  int tid = threadIdx.x;
  int tm = tid & 15, tn = tid >> 4;   // rows tm*8..+7, cols tn*4..+3
  __shared__ float At[32][128];
  __shared__ float Bt[32][64];
  float acc[8][4];
#pragma unroll
  for (int i = 0; i < 8; ++i)
#pragma unroll
    for (int j = 0; j < 4; ++j) acc[i][j] = 0.f;

  for (int kc = 0; kc < 512; kc += 32) {
    // --- stage A (bf16 -> fp32), source: gmax (k<256) or h2 (k>=256) ---
#pragma unroll
    for (int l = 0; l < 4; ++l) {
      int id = tid + (l << 8);        // 0..1023 : 128 rows x 8 (4k groups)
      int m = id >> 3, g = id & 7;
      int row = m0 + m;
      ushort4 v;
      if (kc < 256) {
        unsigned int pp = (unsigned int)row / 20u;
        v = *(const ushort4*)(gmax + (size_t)pp*256 + kc + (g << 2));
      } else {
        v = *(const ushort4*)(h2 + (size_t)row*256 + (kc - 256) + (g << 2));
      }
      int k = g << 2;
      At[k+0][m] = bf2f(v.x);
      At[k+1][m] = bf2f(v.y);
      At[k+2][m] = bf2f(v.z);
      At[k+3][m] = bf2f(v.w);
    }
    // --- stage B (fp32 W3) ---
#pragma unroll
    for (int l = 0; l < 2; ++l) {
      int id = tid + (l << 8);        // 0..511 : k = id>>4, nq = id&15
      int k = id >> 4, nq = id & 15;
      float4 v = *(const float4*)&W3[(size_t)(kc + k)*512 + n0 + (nq << 2)];
      *(float4*)&Bt[k][nq << 2] = v;
    }
    __syncthreads();
#pragma unroll
    for (int k = 0; k < 32; ++k) {
      float4 a0 = *(const float4*)&At[k][tm*8];
      float4 a1 = *(const float4*)&At[k][tm*8 + 4];
      float4 bv = *(const float4*)&Bt[k][tn*4];
      float av[8] = {a0.x,a0.y,a0.z,a0.w,a1.x,a1.y,a1.z,a1.w};
      float bw[4] = {bv.x,bv.y,bv.z,bv.w};
#pragma unroll
      for (int i = 0; i < 8; ++i)
#pragma unroll
        for (int j = 0; j < 4; ++j) acc[i][j] = fmaf(av[i], bw[j], acc[i][j]);
    }
    __syncthreads();
  }
  // epilogue: +b3, write bf16 staging, per-channel partial stats
  float bb[4];
#pragma unroll
  for (int j = 0; j < 4; ++j) bb[j] = b3[n0 + tn*4 + j];
  float csum[4] = {0,0,0,0}, csq[4] = {0,0,0,0};
#pragma unroll
  for (int i = 0; i < 8; ++i) {
    int m = m0 + tm*8 + i;
    float v0 = acc[i][0] + bb[0];
    float v1 = acc[i][1] + bb[1];
    float v2 = acc[i][2] + bb[2];
    float v3 = acc[i][3] + bb[3];
    csum[0] += v0; csum[1] += v1; csum[2] += v2; csum[3] += v3;
    csq[0] = fmaf(v0,v0,csq[0]); csq[1] = fmaf(v1,v1,csq[1]);
    csq[2] = fmaf(v2,v2,csq[2]); csq[3] = fmaf(v3,v3,csq[3]);
    ushort4 o; o.x = f2bf(v0); o.y = f2bf(v1); o.z = f2bf(v2); o.w = f2bf(v3);
    *(ushort4*)(h3 + (size_t)m*512 + n0 + tn*4) = o;
  }
  float* partp = &At[0][0];   // reuse LDS (>= 1024 floats)
#pragma unroll
  for (int j = 0; j < 4; ++j) partp[tm*64 + tn*4 + j] = csum[j];
  __syncthreads();
  if (tid < 64) {
    float s = 0.f;
#pragma unroll
    for (int t = 0; t < 16; ++t) s += partp[t*64 + tid];
    atomicAdd(&s3buck[(size_t)(bm & 63)*1024 + n0 + tid], s);
  }
  __syncthreads();
#pragma unroll
  for (int j = 0; j < 4; ++j) partp[tm*64 + tn*4 + j] = csq[j];
  __syncthreads();
  if (tid < 64) {
    float s = 0.f;
#pragma unroll
    for (int t = 0; t < 16; ++t) s += partp[t*64 + tid];
    atomicAdd(&s3buck[(size_t)(bm & 63)*1024 + 512 + n0 + tid], s);
  }
}

__global__ void bn_prep3(const float* __restrict__ g3, const float* __restrict__ be3,
                         const float* __restrict__ s3buck, float* __restrict__ misc) {
  int c = threadIdx.x;  // 512
  float s = 0.f, q = 0.f;
  for (int b = 0; b < 64; ++b) { s += s3buck[b*1024 + c]; q += s3buck[b*1024 + 512 + c]; }
  const float inv = 1.0f / (float)NSAMP;
  float mu = s * inv;
  float var = q * inv - mu * mu;
  float a = g3[c] / sqrtf(var + 1e-5f);
  misc[256 + c] = a;
  misc[768 + c] = be3[c] - mu * a;
}

// ============================================================
// K7: h4 = relu(a3*h3+d3) @ W4 + b4 with fused max-pool over K=20.
// Tile 80M(4 points) x 128N, micro 5x8. Writes fp32 feature output.
// ============================================================
__global__ __launch_bounds__(256) void gemm4_kernel(const unsigned short* __restrict__ h3,
                                                    const float* __restrict__ W4,
                                                    const float* __restrict__ b4,
                                                    const float* __restrict__ misc,
                                                    float* __restrict__ outf) {
  int bid = blockIdx.x;             // 2048 * 3
  int bm = bid / 3, bn = bid - bm*3;
  int m0 = bm * 80, n0 = bn << 7;
  int tid = threadIdx.x;
  int tm = tid & 15, tn = tid >> 4; // rows tm*5..+4, cols tn*4(+64)
  __shared__ float At[32][81];      // padded stride to break bank conflicts
  __shared__ float Bt[32][128];
  const float* a3 = misc + 256;
  const float* d3 = misc + 768;
  float acc[5][8];
#pragma unroll
  for (int i = 0; i < 5; ++i)
#pragma unroll
    for (int j = 0; j < 8; ++j) acc[i][j] = 0.f;

  for (int kc = 0; kc < 512; kc += 32) {
    // --- stage A: bf16 h3 -> BN3 affine + relu -> fp32 ---
#pragma unroll
    for (int l = 0; l < 3; ++l) {
      int id = tid + (l << 8);
      if (id < 640) {                 // 80 rows x 8 (4k groups)
        int m = id >> 3, g = id & 7;
        ushort4 v = *(const ushort4*)(h3 + (size_t)(m0 + m)*512 + kc + (g << 2));
        int k = g << 2;
        At[k+0][m] = fmaxf(fmaf(a3[kc+k+0], bf2f(v.x), d3[kc+k+0]), 0.f);
        At[k+1][m] = fmaxf(fmaf(a3[kc+k+1], bf2f(v.y), d3[kc+k+1]), 0.f);
        At[k+2][m] = fmaxf(fmaf(a3[kc+k+2], bf2f(v.z), d3[kc+k+2]), 0.f);
        At[k+3][m] = fmaxf(fmaf(a3[kc+k+3], bf2f(v.w), d3[kc+k+3]), 0.f);
      }
    }
    // --- stage B (fp32 W4) ---
#pragma unroll
    for (int l = 0; l < 4; ++l) {
      int id = tid + (l << 8);        // 0..1023: k = id>>5, nq = id&31
      int k = id >> 5, nq = id & 31;
      *(float4*)&Bt[k][nq << 2] =
          *(const float4*)&W4[(size_t)(kc + k)*384 + n0 + (nq << 2)];
    }
    __syncthreads();
#pragma unroll
    for (int k = 0; k < 32; ++k) {
      float a[5];
#pragma unroll
      for (int i = 0; i < 5; ++i) a[i] = At[k][tm*5 + i];
      float4 b0v = *(const float4*)&Bt[k][tn*4];
      float4 b1v = *(const float4*)&Bt[k][64 + tn*4];
      float bw[8] = {b0v.x,b0v.y,b0v.z,b0v.w,b1v.x,b1v.y,b1v.z,b1v.w};
#pragma unroll
      for (int i = 0; i < 5; ++i)
#pragma unroll
        for (int j = 0; j < 8; ++j) acc[i][j] = fmaf(a[i], bw[j], acc[i][j]);
    }
    __syncthreads();
  }
  // --- fused max-pool over K=20 ---
  float pm[8];
#pragma unroll
  for (int j = 0; j < 8; ++j) {
    float v = acc[0][j];
#pragma unroll
    for (int i = 1; i < 5; ++i) v = fmaxf(v, acc[i][j]);
    pm[j] = v;
  }
  float* partp = &At[0][0];   // reuse (needs 2048 floats; At has 2592)
#pragma unroll
  for (int j = 0; j < 4; ++j) {
    partp[tm*128 + tn*4 + j] = pm[j];
    partp[tm*128 + 64 + tn*4 + j] = pm[4 + j];
  }
  __syncthreads();
#pragma unroll
  for (int l = 0; l < 2; ++l) {
    int id = tid + (l << 8);          // 0..511: q = id>>7, col = id&127
    int q = id >> 7, col = id & 127;
    float v = partp[(q*4 + 0)*128 + col];
#pragma unroll
    for (int u = 1; u < 4; ++u) v = fmaxf(v, partp[(q*4 + u)*128 + col]);
    v += b4[n0 + col];
    outf[(size_t)(bm*4 + q)*384 + n0 + col] = v;   // fp32 output
  }
}

// ============================================================
// Workspace layout (~245 MB):
//   0x0000000  idx        8192*20*4   = 640 KB
//   0x00A0000  misc       1280 f32 (a1,d1,a3,d3)
//   0x00A2000  s1buck     32*256 f32  = 32 KB   (zeroed)
//   0x00AA000  s3buck     64*1024 f32 = 256 KB  (zeroed)
//   0x0100000  gmax bf16  8192*256    = 4 MB
//   0x0500000  h2   bf16  163840*256  = 80 MB
//   0x5500000  h3   bf16  163840*512  = 160 MB
// ============================================================
extern "C" void kernel_launch(void* const* d_in, const int* in_sizes, int n_in,
                              void* d_out, int out_size, void* d_ws, size_t ws_size,
                              hipStream_t stream) {
  const float* xyz = (const float*)d_in[0];
  const float* W1  = (const float*)d_in[1];
  const float* b1  = (const float*)d_in[2];
  const float* g1  = (const float*)d_in[3];
  const float* be1 = (const float*)d_in[4];
  const float* W2  = (const float*)d_in[5];
  const float* b2  = (const float*)d_in[6];
  const float* W3  = (const float*)d_in[7];
  const float* b3  = (const float*)d_in[8];
  const float* g3  = (const float*)d_in[9];
  const float* be3 = (const float*)d_in[10];
  const float* W4  = (const float*)d_in[11];
  const float* b4  = (const float*)d_in[12];

  char* ws = (char*)d_ws;
  int*            idx    = (int*)ws;
  float*          misc   = (float*)(ws + 0xA0000);
  float*          s1buck = (float*)(ws + 0xA2000);
  float*          s3buck = (float*)(ws + 0xAA000);
  unsigned short* gmax   = (unsigned short*)(ws + 0x100000);
  unsigned short* h2     = (unsigned short*)(ws + 0x500000);
  unsigned short* h3     = (unsigned short*)(ws + 0x5500000ULL);

  float* ofp   = (float*)d_out;
  float* oxyz  = ofp;             // 24576 fp32
  float* ofeat = ofp + 24576;     // 8192*384 fp32

  // zero the stat buckets (ws is poisoned before every launch)
  hipMemsetAsync(ws + 0xA2000, 0, 0x48000, stream);

  knn_kernel<<<NPTS, 256, 0, stream>>>(xyz, idx, oxyz);
  h1_stats_kernel<<<NSAMP/512, 256, 0, stream>>>(xyz, idx, W1, b1, s1buck);
  bn_prep1<<<1, 128, 0, stream>>>(g1, be1, s1buck, misc);
  h2_kernel<<<NPTS, 256, 0, stream>>>(xyz, idx, W1, b1, W2, b2, misc, h2, gmax);
  gemm3_kernel<<<(NSAMP/128)*8, 256, 0, stream>>>(h2, gmax, W3, b3, h3, s3buck);
  bn_prep3<<<1, 512, 0, stream>>>(g3, be3, s3buck, misc);
  gemm4_kernel<<<(NSAMP/80)*3, 256, 0, stream>>>(h3, W4, b4, misc, ofeat);
}

// Round 4
// 862.211 us; speedup vs baseline: 2.7699x; 2.7699x over previous
//
#include <hip/hip_runtime.h>
#include <float.h>

// Problem constants: B=2, N=4096, K=20, H=384
// Inputs: fp32 arrays (values bf16-quantized by harness). Output: fp32.
#define NPTS_B 4096
#define NPTS 8192            // B*N
#define KNN 20
#define NSAMP (NPTS*KNN)     // 163840

typedef __attribute__((ext_vector_type(8))) short bf16x8;
typedef __attribute__((ext_vector_type(4))) float f32x4;

// -------- bf16 helpers (internal staging only) --------
static __device__ __forceinline__ float bf2f(unsigned short u) {
  return __uint_as_float(((unsigned int)u) << 16);
}
static __device__ __forceinline__ unsigned short f2bf(float f) {
  unsigned int u = __float_as_uint(f);
  u += 0x7fffu + ((u >> 16) & 1u);
  return (unsigned short)(u >> 16);
}

// ============================================================
// K0: weight prep — W3 (512x512) -> W3T bf16 [n][k]; W4 (512x384) -> W4T
// bf16 [n][k]. Inputs are bf16-grid values in fp32 -> conversion EXACT.
// ============================================================
__global__ __launch_bounds__(256) void wprep_kernel(const float* __restrict__ W3,
                                                    const float* __restrict__ W4,
                                                    unsigned short* __restrict__ W3T,
                                                    unsigned short* __restrict__ W4T) {
  int id = blockIdx.x * 256 + threadIdx.x;
  if (id < 512*512) {
    int n = id >> 9, k = id & 511;
    W3T[id] = f2bf(W3[k*512 + n]);
  } else {
    int id2 = id - 512*512;          // < 384*512
    int n = id2 >> 9, k = id2 & 511;
    W4T[id2] = f2bf(W4[k*384 + n]);
  }
}

// ============================================================
// K1: KNN (one block per point). d2 = sq_i + sq_j - 2*dot, fp contract off.
// Selection: 20 rounds of lex-min (d2, j) == top_k stable tie-break.
// Also writes xyz passthrough output (exact fp32 copy).
// ============================================================
__global__ __launch_bounds__(256) void knn_kernel(const float* __restrict__ xyz,
                                                  int* __restrict__ idx,
                                                  float* __restrict__ out_xyz) {
#pragma clang fp contract(off)
  int p = blockIdx.x;            // 0..8191
  int base = p & ~4095;          // batch base row
  int tid = threadIdx.x;
  const float* xb = xyz + (size_t)base * 3;
  float xi0 = xyz[p*3+0], xi1 = xyz[p*3+1], xi2 = xyz[p*3+2];
  float sqi = (xi0*xi0 + xi1*xi1) + xi2*xi2;
  float dist[16];
#pragma unroll
  for (int u = 0; u < 16; ++u) {
    int j = tid + (u << 8);
    float a0 = xb[j*3+0], a1 = xb[j*3+1], a2 = xb[j*3+2];
    float sqj = (a0*a0 + a1*a1) + a2*a2;
    float dt  = (xi0*a0 + xi1*a1) + xi2*a2;
    dist[u] = (sqi + sqj) - 2.0f*dt;
  }
  __shared__ float wd[4];
  __shared__ int   wj[4];
  __shared__ int   win_j;
  for (int r = 0; r < 20; ++r) {
    float bd = dist[0]; int bj = tid;
#pragma unroll
    for (int u = 1; u < 16; ++u) {
      int j = tid + (u << 8);
      if (dist[u] < bd || (dist[u] == bd && j < bj)) { bd = dist[u]; bj = j; }
    }
#pragma unroll
    for (int off = 32; off; off >>= 1) {
      float od = __shfl_down(bd, off);
      int   oj = __shfl_down(bj, off);
      if (od < bd || (od == bd && oj < bj)) { bd = od; bj = oj; }
    }
    if ((tid & 63) == 0) { wd[tid >> 6] = bd; wj[tid >> 6] = bj; }
    __syncthreads();
    if (tid == 0) {
      float d0 = wd[0]; int j0 = wj[0];
#pragma unroll
      for (int w = 1; w < 4; ++w)
        if (wd[w] < d0 || (wd[w] == d0 && wj[w] < j0)) { d0 = wd[w]; j0 = wj[w]; }
      win_j = j0;
      idx[p*20 + r] = base + j0;   // GLOBAL row index
    }
    __syncthreads();
    int jw = win_j;
    int slot = jw >> 8;
    if ((jw & 255) == tid) {
#pragma unroll
      for (int u = 0; u < 16; ++u) if (u == slot) dist[u] = FLT_MAX;
    }
  }
  if (tid < 3) out_xyz[p*3 + tid] = xyz[p*3 + tid];   // exact fp32 copy
}

// ============================================================
// K2: BN1 statistics — recompute h1 = e@W1 + b1 per sample,
// accumulate per-channel sum / sumsq into 32 buckets.
// ============================================================
__global__ __launch_bounds__(256) void h1_stats_kernel(const float* __restrict__ xyz,
                                                       const int* __restrict__ idx,
                                                       const float* __restrict__ W1,
                                                       const float* __restrict__ b1,
                                                       float* __restrict__ s1buck) {
  int blk = blockIdx.x;         // 320 blocks * 512 samples
  int tid = threadIdx.x;
  int c = tid & 127, half = tid >> 7;
  float w[6];
#pragma unroll
  for (int d = 0; d < 6; ++d) w[d] = W1[d*128 + c];
  float bb = b1[c];
  float sum = 0.f, sq = 0.f;
  int s0 = blk * 512;
  for (int u = 0; u < 256; ++u) {
    int s = s0 + (u << 1) + half;
    unsigned int p = (unsigned int)s / 20u;
    int jg = idx[s];
    float xi0 = xyz[p*3+0], xi1 = xyz[p*3+1], xi2 = xyz[p*3+2];
    float e0 = xyz[jg*3+0] - xi0;
    float e1 = xyz[jg*3+1] - xi1;
    float e2 = xyz[jg*3+2] - xi2;
    float h = bb;
    h = fmaf(e0, w[0], h); h = fmaf(e1, w[1], h); h = fmaf(e2, w[2], h);
    h = fmaf(xi0, w[3], h); h = fmaf(xi1, w[4], h); h = fmaf(xi2, w[5], h);
    sum += h; sq = fmaf(h, h, sq);
  }
  __shared__ float ls[128], lq[128];
  if (!half) { ls[c] = sum; lq[c] = sq; }
  __syncthreads();
  if (half) {
    int bkt = (blk & 31) * 256;
    atomicAdd(&s1buck[bkt + c], ls[c] + sum);
    atomicAdd(&s1buck[bkt + 128 + c], lq[c] + sq);
  }
}

__global__ void bn_prep1(const float* __restrict__ g1, const float* __restrict__ be1,
                         const float* __restrict__ s1buck, float* __restrict__ misc) {
  int c = threadIdx.x;  // 128
  float s = 0.f, q = 0.f;
  for (int b = 0; b < 32; ++b) { s += s1buck[b*256 + c]; q += s1buck[b*256 + 128 + c]; }
  const float inv = 1.0f / (float)NSAMP;
  float mu = s * inv;
  float var = q * inv - mu * mu;
  float a = g1[c] / sqrtf(var + 1e-5f);
  misc[c] = a;
  misc[128 + c] = be1[c] - mu * a;
}

// ============================================================
// K4: per point: edge -> h1 (BN1+ReLU) -> h2 (128->256) -> gmax over K.
// Writes h2 and gmax as bf16 staging. Block = point, thread = h2 channel.
// ============================================================
__global__ __launch_bounds__(256) void h2_kernel(const float* __restrict__ xyz,
                                                 const int* __restrict__ idx,
                                                 const float* __restrict__ W1,
                                                 const float* __restrict__ b1,
                                                 const float* __restrict__ W2,
                                                 const float* __restrict__ b2,
                                                 const float* __restrict__ misc,
                                                 unsigned short* __restrict__ h2out,
                                                 unsigned short* __restrict__ gmaxout) {
  int p = blockIdx.x;
  int tid = threadIdx.x;
  __shared__ float e[20][6];
  __shared__ float h1t[128*20];  // [c][n]
  if (tid < 20) {
    int jg = idx[p*20 + tid];
    float xi0 = xyz[p*3+0], xi1 = xyz[p*3+1], xi2 = xyz[p*3+2];
    e[tid][0] = xyz[jg*3+0] - xi0;
    e[tid][1] = xyz[jg*3+1] - xi1;
    e[tid][2] = xyz[jg*3+2] - xi2;
    e[tid][3] = xi0; e[tid][4] = xi1; e[tid][5] = xi2;
  }
  __syncthreads();
#pragma unroll
  for (int u = 0; u < 10; ++u) {
    int id = tid + (u << 8);           // 0..2559 = 128c * 20n
    int c = (unsigned int)id / 20u;
    int n = id - c * 20;
    float v = b1[c];
#pragma unroll
    for (int d = 0; d < 6; ++d) v = fmaf(e[n][d], W1[d*128 + c], v);
    v = fmaxf(fmaf(misc[c], v, misc[128 + c]), 0.f);
    h1t[c*20 + n] = v;
  }
  __syncthreads();
  int c = tid;
  float acc[20];
  float bb = b2[c];
#pragma unroll
  for (int n = 0; n < 20; ++n) acc[n] = bb;
  const float* w2c = W2 + c;
#pragma unroll 2
  for (int k = 0; k < 128; ++k) {
    float w = w2c[k*256];
    const float4* hp = (const float4*)&h1t[k*20];
    float4 h0 = hp[0], h1v = hp[1], h2v = hp[2], h3v = hp[3], h4v = hp[4];
    acc[0]  = fmaf(h0.x, w, acc[0]);  acc[1]  = fmaf(h0.y, w, acc[1]);
    acc[2]  = fmaf(h0.z, w, acc[2]);  acc[3]  = fmaf(h0.w, w, acc[3]);
    acc[4]  = fmaf(h1v.x, w, acc[4]); acc[5]  = fmaf(h1v.y, w, acc[5]);
    acc[6]  = fmaf(h1v.z, w, acc[6]); acc[7]  = fmaf(h1v.w, w, acc[7]);
    acc[8]  = fmaf(h2v.x, w, acc[8]); acc[9]  = fmaf(h2v.y, w, acc[9]);
    acc[10] = fmaf(h2v.z, w, acc[10]); acc[11] = fmaf(h2v.w, w, acc[11]);
    acc[12] = fmaf(h3v.x, w, acc[12]); acc[13] = fmaf(h3v.y, w, acc[13]);
    acc[14] = fmaf(h3v.z, w, acc[14]); acc[15] = fmaf(h3v.w, w, acc[15]);
    acc[16] = fmaf(h4v.x, w, acc[16]); acc[17] = fmaf(h4v.y, w, acc[17]);
    acc[18] = fmaf(h4v.z, w, acc[18]); acc[19] = fmaf(h4v.w, w, acc[19]);
  }
  float g = acc[0];
#pragma unroll
  for (int n = 1; n < 20; ++n) g = fmaxf(g, acc[n]);
  gmaxout[(size_t)p*256 + c] = f2bf(g);
#pragma unroll
  for (int n = 0; n < 20; ++n)
    h2out[(size_t)(p*20 + n)*256 + c] = f2bf(acc[n]);
}

// ============================================================
// K5: MFMA GEMM: h3 = [gmax | h2] @ W3 + b3 (163840x512x512), bf16 MFMA.
// Tile 128M x 128N, 4 waves (2m x 2n), each wave 64x64 = 4x4 16x16 frags.
// A k<256 from gmax[row/20], k>=256 from h2[row]. Fused BN3 stats.
// Frag layouts (verified, cdna_hip_programming §3):
//   A: lane holds A[m=lane&15][k=(lane>>4)*8+j]; B: B[k=(lane>>4)*8+j][n=lane&15]
//   C/D: row=(lane>>4)*4+reg, col=lane&15
// ============================================================
__global__ __launch_bounds__(256) void gemm3_kernel(const unsigned short* __restrict__ h2,
                                                    const unsigned short* __restrict__ gmax,
                                                    const unsigned short* __restrict__ W3T,
                                                    const float* __restrict__ b3,
                                                    unsigned short* __restrict__ h3,
                                                    float* __restrict__ s3buck) {
  int bid = blockIdx.x;               // 1280 m * 4 n
  int bn = bid & 3, bm = bid >> 2;
  int m0 = bm << 7, n0 = bn << 7;
  int tid = threadIdx.x;
  int lane = tid & 63, w = tid >> 6;
  int mw = w >> 1, nw = w & 1;
  int lr = lane & 15, lg = lane >> 4;
  __shared__ __align__(16) unsigned short As[128][32];
  __shared__ __align__(16) unsigned short Bs[128][32];
  __shared__ float ssum[128], ssq[128];
  f32x4 acc[4][4] = {};

  for (int kc = 0; kc < 512; kc += 32) {
#pragma unroll
    for (int l = 0; l < 2; ++l) {
      int id = tid + (l << 8);        // 0..511 : 128 rows x 4 kgroups
      int row = id >> 2, kg = id & 3;
      int grow = m0 + row;
      const unsigned short* src;
      if (kc < 256) {
        unsigned int pp = (unsigned int)grow / 20u;
        src = gmax + (size_t)pp*256 + kc + (kg << 3);
      } else {
        src = h2 + (size_t)grow*256 + (kc - 256) + (kg << 3);
      }
      *(uint4*)&As[row][kg << 3] = *(const uint4*)src;
    }
#pragma unroll
    for (int l = 0; l < 2; ++l) {
      int id = tid + (l << 8);
      int row = id >> 2, kg = id & 3;
      *(uint4*)&Bs[row][kg << 3] =
          *(const uint4*)(W3T + (size_t)(n0 + row)*512 + kc + (kg << 3));
    }
    __syncthreads();
    bf16x8 a[4], b[4];
#pragma unroll
    for (int t = 0; t < 4; ++t)
      a[t] = *(const bf16x8*)&As[mw*64 + t*16 + lr][lg << 3];
#pragma unroll
    for (int t = 0; t < 4; ++t)
      b[t] = *(const bf16x8*)&Bs[nw*64 + t*16 + lr][lg << 3];
#pragma unroll
    for (int i = 0; i < 4; ++i)
#pragma unroll
      for (int j = 0; j < 4; ++j)
        acc[i][j] = __builtin_amdgcn_mfma_f32_16x16x32_bf16(a[i], b[j], acc[i][j], 0, 0, 0);
    __syncthreads();
  }

  // epilogue: +b3, bf16 store, fused BN3 stats
  if (tid < 128) { ssum[tid] = 0.f; ssq[tid] = 0.f; }
  __syncthreads();
#pragma unroll
  for (int j = 0; j < 4; ++j) {
    int colL = nw*64 + j*16 + lr;     // col within block tile
    int col = n0 + colL;
    float b3v = b3[col];
    float sumv = 0.f, sqv = 0.f;
#pragma unroll
    for (int i = 0; i < 4; ++i) {
      int rbase = m0 + mw*64 + i*16 + lg*4;
#pragma unroll
      for (int r = 0; r < 4; ++r) {
        float v = acc[i][j][r] + b3v;
        h3[(size_t)(rbase + r)*512 + col] = f2bf(v);
        sumv += v; sqv = fmaf(v, v, sqv);
      }
    }
    sumv += __shfl_xor(sumv, 16); sumv += __shfl_xor(sumv, 32);
    sqv  += __shfl_xor(sqv, 16);  sqv  += __shfl_xor(sqv, 32);
    if (lg == 0) {
      atomicAdd(&ssum[colL], sumv);
      atomicAdd(&ssq[colL], sqv);
    }
  }
  __syncthreads();
  if (tid < 128) {
    int bkt = (bid & 63) * 1024;
    atomicAdd(&s3buck[bkt + n0 + tid], ssum[tid]);
    atomicAdd(&s3buck[bkt + 512 + n0 + tid], ssq[tid]);
  }
}

__global__ void bn_prep3(const float* __restrict__ g3, const float* __restrict__ be3,
                         const float* __restrict__ s3buck, float* __restrict__ misc) {
  int c = threadIdx.x;  // 512
  float s = 0.f, q = 0.f;
  for (int b = 0; b < 64; ++b) { s += s3buck[b*1024 + c]; q += s3buck[b*1024 + 512 + c]; }
  const float inv = 1.0f / (float)NSAMP;
  float mu = s * inv;
  float var = q * inv - mu * mu;
  float a = g3[c] / sqrtf(var + 1e-5f);
  misc[256 + c] = a;
  misc[768 + c] = be3[c] - mu * a;
}

// ============================================================
// K7: MFMA GEMM: h4 = relu(a3*h3+d3) @ W4 (+b4) with FUSED max-pool over
// K=20. M-tile 160 (8 points), N-tile 128. 4 waves (2m x 2n), each wave
// 80x64 = 5x4 frags. Point boundaries (mult of 20) align with 4-row
// C-fragment reg groups (gcd(16,20)=4) -> per-lane reg-max is point-pure.
// ============================================================
__global__ __launch_bounds__(256) void gemm4_kernel(const unsigned short* __restrict__ h3,
                                                    const unsigned short* __restrict__ W4T,
                                                    const float* __restrict__ b4,
                                                    const float* __restrict__ misc,
                                                    float* __restrict__ outf) {
  int bid = blockIdx.x;             // 1024 m * 3 n
  int bm = bid / 3, bn = bid - bm*3;
  int m0 = bm * 160, n0 = bn << 7;
  int tid = threadIdx.x;
  int lane = tid & 63, w = tid >> 6;
  int mw = w >> 1, nw = w & 1;
  int lr = lane & 15, lg = lane >> 4;
  __shared__ __align__(16) unsigned short As[160][32];
  __shared__ __align__(16) unsigned short Bs[128][32];
  __shared__ float af[512], df[512];
  __shared__ float pool[40][132];   // padded stride (bank spread)
#pragma unroll
  for (int l = 0; l < 2; ++l) {
    int id = tid + (l << 8);
    af[id] = misc[256 + id];
    df[id] = misc[768 + id];
  }
  __syncthreads();
  f32x4 acc[5][4] = {};

  for (int kc = 0; kc < 512; kc += 32) {
#pragma unroll
    for (int l = 0; l < 3; ++l) {
      int id = tid + (l << 8);
      if (id < 640) {                 // 160 rows x 4 kgroups
        int row = id >> 2, kg = id & 3;
        uint4 v = *(const uint4*)(h3 + (size_t)(m0 + row)*512 + kc + (kg << 3));
        int kb = kc + (kg << 3);
        unsigned int o[4];
#pragma unroll
        for (int q = 0; q < 4; ++q) {
          unsigned int u = ((const unsigned int*)&v)[q];
          float lo = bf2f((unsigned short)(u & 0xffffu));
          float hi = bf2f((unsigned short)(u >> 16));
          int k0 = kb + q*2;
          lo = fmaxf(fmaf(af[k0],   lo, df[k0]),   0.f);
          hi = fmaxf(fmaf(af[k0+1], hi, df[k0+1]), 0.f);
          o[q] = (unsigned int)f2bf(lo) | ((unsigned int)f2bf(hi) << 16);
        }
        *(uint4*)&As[row][kg << 3] = *(const uint4*)o;
      }
    }
#pragma unroll
    for (int l = 0; l < 2; ++l) {
      int id = tid + (l << 8);
      int row = id >> 2, kg = id & 3;
      *(uint4*)&Bs[row][kg << 3] =
          *(const uint4*)(W4T + (size_t)(n0 + row)*512 + kc + (kg << 3));
    }
    __syncthreads();
    bf16x8 a[5], b[4];
#pragma unroll
    for (int t = 0; t < 5; ++t)
      a[t] = *(const bf16x8*)&As[mw*80 + t*16 + lr][lg << 3];
#pragma unroll
    for (int t = 0; t < 4; ++t)
      b[t] = *(const bf16x8*)&Bs[nw*64 + t*16 + lr][lg << 3];
#pragma unroll
    for (int i = 0; i < 5; ++i)
#pragma unroll
      for (int j = 0; j < 4; ++j)
        acc[i][j] = __builtin_amdgcn_mfma_f32_16x16x32_bf16(a[i], b[j], acc[i][j], 0, 0, 0);
    __syncthreads();
  }

  // fused max-pool: per-lane reg-max (4 rows, point-pure) -> LDS -> pool
#pragma unroll
  for (int i = 0; i < 5; ++i)
#pragma unroll
    for (int j = 0; j < 4; ++j) {
      float m = fmaxf(fmaxf(acc[i][j][0], acc[i][j][1]),
                      fmaxf(acc[i][j][2], acc[i][j][3]));
      pool[mw*20 + i*4 + lg][nw*64 + j*16 + lr] = m;
    }
  __syncthreads();
#pragma unroll
  for (int l = 0; l < 4; ++l) {
    int id = tid + (l << 8);          // 0..1023 : 8 points x 128 cols
    int q = id >> 7, c = id & 127;
    int mwq = q >> 2, ql = q & 3;
    float v = pool[mwq*20 + ql*5][c];
#pragma unroll
    for (int u = 1; u < 5; ++u) v = fmaxf(v, pool[mwq*20 + ql*5 + u][c]);
    outf[(size_t)(bm*8 + q)*384 + n0 + c] = v + b4[n0 + c];
  }
}

// ============================================================
// Workspace layout (fits in proven <= 0xF600000 ~ 247 MiB):
//   0x0000000  idx        8192*20*4  = 640 KB
//   0x00A0000  misc       1280 f32
//   0x00A2000  s1buck     32 KB   (zeroed)
//   0x00AA000  s3buck     256 KB  (zeroed)
//   0x00F0000  W3T bf16   512*512*2 = 512 KB
//   0x0170000  W4T bf16   384*512*2 = 384 KB
//   0x0200000  gmax bf16  8192*256  = 4 MB
//   0x0600000  h2   bf16  163840*256 = 80 MB
//   0x5600000  h3   bf16  163840*512 = 160 MB  -> end 0xF600000
// ============================================================
extern "C" void kernel_launch(void* const* d_in, const int* in_sizes, int n_in,
                              void* d_out, int out_size, void* d_ws, size_t ws_size,
                              hipStream_t stream) {
  const float* xyz = (const float*)d_in[0];
  const float* W1  = (const float*)d_in[1];
  const float* b1  = (const float*)d_in[2];
  const float* g1  = (const float*)d_in[3];
  const float* be1 = (const float*)d_in[4];
  const float* W2  = (const float*)d_in[5];
  const float* b2  = (const float*)d_in[6];
  const float* W3  = (const float*)d_in[7];
  const float* b3  = (const float*)d_in[8];
  const float* g3  = (const float*)d_in[9];
  const float* be3 = (const float*)d_in[10];
  const float* W4  = (const float*)d_in[11];
  const float* b4  = (const float*)d_in[12];

  char* ws = (char*)d_ws;
  int*            idx    = (int*)ws;
  float*          misc   = (float*)(ws + 0xA0000);
  float*          s1buck = (float*)(ws + 0xA2000);
  float*          s3buck = (float*)(ws + 0xAA000);
  unsigned short* W3T    = (unsigned short*)(ws + 0xF0000);
  unsigned short* W4T    = (unsigned short*)(ws + 0x170000);
  unsigned short* gmax   = (unsigned short*)(ws + 0x200000);
  unsigned short* h2     = (unsigned short*)(ws + 0x600000);
  unsigned short* h3     = (unsigned short*)(ws + 0x5600000ULL);

  float* ofp   = (float*)d_out;
  float* oxyz  = ofp;             // 24576 fp32
  float* ofeat = ofp + 24576;     // 8192*384 fp32

  hipMemsetAsync(ws + 0xA2000, 0, 0x48000, stream);   // zero stat buckets

  wprep_kernel<<<(512*512 + 384*512)/256, 256, 0, stream>>>(W3, W4, W3T, W4T);
  knn_kernel<<<NPTS, 256, 0, stream>>>(xyz, idx, oxyz);
  h1_stats_kernel<<<NSAMP/512, 256, 0, stream>>>(xyz, idx, W1, b1, s1buck);
  bn_prep1<<<1, 128, 0, stream>>>(g1, be1, s1buck, misc);
  h2_kernel<<<NPTS, 256, 0, stream>>>(xyz, idx, W1, b1, W2, b2, misc, h2, gmax);
  gemm3_kernel<<<(NSAMP/128)*4, 256, 0, stream>>>(h2, gmax, W3T, b3, h3, s3buck);
  bn_prep3<<<1, 512, 0, stream>>>(g3, be3, s3buck, misc);
  gemm4_kernel<<<(NPTS/8)*3, 256, 0, stream>>>(h3, W4T, b4, misc, ofeat);
}

// Round 5
// 709.123 us; speedup vs baseline: 3.3679x; 1.2159x over previous
//
#include <hip/hip_runtime.h>
#include <float.h>

// Problem constants: B=2, N=4096, K=20, H=384
// Inputs: fp32 arrays (values bf16-quantized by harness). Output: fp32.
#define NPTS_B 4096
#define NPTS 8192            // B*N
#define KNN 20
#define NSAMP (NPTS*KNN)     // 163840

typedef __attribute__((ext_vector_type(8))) short bf16x8;
typedef __attribute__((ext_vector_type(4))) float f32x4;

// -------- bf16 helpers (internal staging only) --------
static __device__ __forceinline__ float bf2f(unsigned short u) {
  return __uint_as_float(((unsigned int)u) << 16);
}
static __device__ __forceinline__ unsigned short f2bf(float f) {
  unsigned int u = __float_as_uint(f);
  u += 0x7fffu + ((u >> 16) & 1u);
  return (unsigned short)(u >> 16);
}
static __device__ __forceinline__ unsigned long long u64min(unsigned long long a,
                                                           unsigned long long b) {
  return a < b ? a : b;
}
static __device__ __forceinline__ unsigned long long shflx64(unsigned long long v, int m) {
  int lo = __shfl_xor((int)(unsigned int)(v & 0xffffffffull), m);
  int hi = __shfl_xor((int)(unsigned int)(v >> 32), m);
  return ((unsigned long long)(unsigned int)hi << 32) | (unsigned int)lo;
}

// ============================================================
// K0: weight prep — W3 (512x512) -> W3T bf16 [n][k]; W4 (512x384) -> W4T
// bf16 [n][k]. Inputs are bf16-grid values in fp32 -> conversion EXACT.
// ============================================================
__global__ __launch_bounds__(256) void wprep_kernel(const float* __restrict__ W3,
                                                    const float* __restrict__ W4,
                                                    unsigned short* __restrict__ W3T,
                                                    unsigned short* __restrict__ W4T) {
  int id = blockIdx.x * 256 + threadIdx.x;
  if (id < 512*512) {
    int n = id >> 9, k = id & 511;
    W3T[id] = f2bf(W3[k*512 + n]);
  } else {
    int id2 = id - 512*512;          // < 384*512
    int n = id2 >> 9, k = id2 & 511;
    W4T[id2] = f2bf(W4[k*384 + n]);
  }
}

// ============================================================
// K1: KNN (one block per point). d2 = sq_i + sq_j - 2*dot, fp contract off.
// Candidates packed as u64 (d2_bits<<32 | j): single u64 compare == lex
// (d2, idx) order (d2 >= +0.0 so float bits are monotone). 20 rounds of
// extract-min with INCREMENTAL cached minima:
//   - each thread caches its local min over its 16 candidates
//   - each wave caches its wave-min (all lanes, via butterfly)
//   - per round: all threads 4-way-min the wave-minima (LDS, double-
//     buffered -> ONE barrier/round); only the winner thread rescans;
//     only the owner wave re-reduces.
// Downstream is neighbor-order-invariant, so set-equality with top_k
// suffices; u64 order matches top_k's tie-break anyway.
// Also writes xyz passthrough output (exact fp32 copy).
// ============================================================
__global__ __launch_bounds__(256) void knn_kernel(const float* __restrict__ xyz,
                                                  int* __restrict__ idx,
                                                  float* __restrict__ out_xyz) {
#pragma clang fp contract(off)
  int p = blockIdx.x;            // 0..8191
  int base = p & ~4095;          // batch base row
  int tid = threadIdx.x;
  int wv = tid >> 6;
  int ln = tid & 63;
  const float* xb = xyz + (size_t)base * 3;
  float xi0 = xyz[p*3+0], xi1 = xyz[p*3+1], xi2 = xyz[p*3+2];
  float sqi = (xi0*xi0 + xi1*xi1) + xi2*xi2;

  unsigned long long cand[16];
#pragma unroll
  for (int u = 0; u < 16; ++u) {
    int j = tid + (u << 8);
    float a0 = xb[j*3+0], a1 = xb[j*3+1], a2 = xb[j*3+2];
    float sqj = (a0*a0 + a1*a1) + a2*a2;
    float dt  = (xi0*a0 + xi1*a1) + xi2*a2;
    float d2  = (sqi + sqj) - 2.0f*dt;
    cand[u] = ((unsigned long long)__float_as_uint(d2) << 32) | (unsigned int)j;
  }
  // per-thread local min (tree)
  unsigned long long myloc;
  {
    unsigned long long t[8];
#pragma unroll
    for (int u = 0; u < 8; ++u) t[u] = u64min(cand[u], cand[u + 8]);
#pragma unroll
    for (int u = 0; u < 4; ++u) t[u] = u64min(t[u], t[u + 4]);
    t[0] = u64min(t[0], t[2]); t[1] = u64min(t[1], t[3]);
    myloc = u64min(t[0], t[1]);
  }
  // wave butterfly -> all lanes hold wave-min
  unsigned long long wmreg = myloc;
#pragma unroll
  for (int off = 1; off < 64; off <<= 1) wmreg = u64min(wmreg, shflx64(wmreg, off));

  __shared__ __align__(16) unsigned long long wbuf[2][4];
  __shared__ int outbuf[20];
  if (ln == 0) wbuf[0][wv] = wmreg;
  __syncthreads();

  for (int r = 0; r < 20; ++r) {
    int cur = r & 1;
    unsigned long long w0 = wbuf[cur][0], w1 = wbuf[cur][1];
    unsigned long long w2 = wbuf[cur][2], w3 = wbuf[cur][3];
    unsigned long long g = u64min(u64min(w0, w1), u64min(w2, w3));
    int wj = (int)(unsigned int)(g & 0xffffffffu);      // winning candidate j
    // winner thread: record, invalidate, rescan
    if (tid == (wj & 255)) {
      outbuf[r] = base + wj;
      unsigned long long m = ~0ull;
#pragma unroll
      for (int u = 0; u < 16; ++u) {
        if (cand[u] == g) cand[u] = ~0ull;
        m = u64min(m, cand[u]);
      }
      myloc = m;
    }
    // owner wave: re-reduce its wave-min
    if (wv == ((wj >> 6) & 3)) {
      unsigned long long t = myloc;
#pragma unroll
      for (int off = 1; off < 64; off <<= 1) t = u64min(t, shflx64(t, off));
      wmreg = t;
    }
    // every wave publishes its (possibly unchanged) wave-min to next buffer
    if (ln == 0) wbuf[cur ^ 1][wv] = wmreg;
    __syncthreads();
  }
  if (tid < 20) idx[p*20 + tid] = outbuf[tid];
  if (tid < 3) out_xyz[p*3 + tid] = xyz[p*3 + tid];   // exact fp32 copy
}

// ============================================================
// K2: BN1 statistics — recompute h1 = e@W1 + b1 per sample,
// accumulate per-channel sum / sumsq into 32 buckets.
// ============================================================
__global__ __launch_bounds__(256) void h1_stats_kernel(const float* __restrict__ xyz,
                                                       const int* __restrict__ idx,
                                                       const float* __restrict__ W1,
                                                       const float* __restrict__ b1,
                                                       float* __restrict__ s1buck) {
  int blk = blockIdx.x;         // 320 blocks * 512 samples
  int tid = threadIdx.x;
  int c = tid & 127, half = tid >> 7;
  float w[6];
#pragma unroll
  for (int d = 0; d < 6; ++d) w[d] = W1[d*128 + c];
  float bb = b1[c];
  float sum = 0.f, sq = 0.f;
  int s0 = blk * 512;
  for (int u = 0; u < 256; ++u) {
    int s = s0 + (u << 1) + half;
    unsigned int p = (unsigned int)s / 20u;
    int jg = idx[s];
    float xi0 = xyz[p*3+0], xi1 = xyz[p*3+1], xi2 = xyz[p*3+2];
    float e0 = xyz[jg*3+0] - xi0;
    float e1 = xyz[jg*3+1] - xi1;
    float e2 = xyz[jg*3+2] - xi2;
    float h = bb;
    h = fmaf(e0, w[0], h); h = fmaf(e1, w[1], h); h = fmaf(e2, w[2], h);
    h = fmaf(xi0, w[3], h); h = fmaf(xi1, w[4], h); h = fmaf(xi2, w[5], h);
    sum += h; sq = fmaf(h, h, sq);
  }
  __shared__ float ls[128], lq[128];
  if (!half) { ls[c] = sum; lq[c] = sq; }
  __syncthreads();
  if (half) {
    int bkt = (blk & 31) * 256;
    atomicAdd(&s1buck[bkt + c], ls[c] + sum);
    atomicAdd(&s1buck[bkt + 128 + c], lq[c] + sq);
  }
}

__global__ void bn_prep1(const float* __restrict__ g1, const float* __restrict__ be1,
                         const float* __restrict__ s1buck, float* __restrict__ misc) {
  int c = threadIdx.x;  // 128
  float s = 0.f, q = 0.f;
  for (int b = 0; b < 32; ++b) { s += s1buck[b*256 + c]; q += s1buck[b*256 + 128 + c]; }
  const float inv = 1.0f / (float)NSAMP;
  float mu = s * inv;
  float var = q * inv - mu * mu;
  float a = g1[c] / sqrtf(var + 1e-5f);
  misc[c] = a;
  misc[128 + c] = be1[c] - mu * a;
}

// ============================================================
// K4: per point: edge -> h1 (BN1+ReLU) -> h2 (128->256) -> gmax over K.
// Writes h2 and gmax as bf16 staging. Block = point, thread = h2 channel.
// ============================================================
__global__ __launch_bounds__(256) void h2_kernel(const float* __restrict__ xyz,
                                                 const int* __restrict__ idx,
                                                 const float* __restrict__ W1,
                                                 const float* __restrict__ b1,
                                                 const float* __restrict__ W2,
                                                 const float* __restrict__ b2,
                                                 const float* __restrict__ misc,
                                                 unsigned short* __restrict__ h2out,
                                                 unsigned short* __restrict__ gmaxout) {
  int p = blockIdx.x;
  int tid = threadIdx.x;
  __shared__ float e[20][6];
  __shared__ float h1t[128*20];  // [c][n]
  if (tid < 20) {
    int jg = idx[p*20 + tid];
    float xi0 = xyz[p*3+0], xi1 = xyz[p*3+1], xi2 = xyz[p*3+2];
    e[tid][0] = xyz[jg*3+0] - xi0;
    e[tid][1] = xyz[jg*3+1] - xi1;
    e[tid][2] = xyz[jg*3+2] - xi2;
    e[tid][3] = xi0; e[tid][4] = xi1; e[tid][5] = xi2;
  }
  __syncthreads();
#pragma unroll
  for (int u = 0; u < 10; ++u) {
    int id = tid + (u << 8);           // 0..2559 = 128c * 20n
    int c = (unsigned int)id / 20u;
    int n = id - c * 20;
    float v = b1[c];
#pragma unroll
    for (int d = 0; d < 6; ++d) v = fmaf(e[n][d], W1[d*128 + c], v);
    v = fmaxf(fmaf(misc[c], v, misc[128 + c]), 0.f);
    h1t[c*20 + n] = v;
  }
  __syncthreads();
  int c = tid;
  float acc[20];
  float bb = b2[c];
#pragma unroll
  for (int n = 0; n < 20; ++n) acc[n] = bb;
  const float* w2c = W2 + c;
#pragma unroll 2
  for (int k = 0; k < 128; ++k) {
    float w = w2c[k*256];
    const float4* hp = (const float4*)&h1t[k*20];
    float4 h0 = hp[0], h1v = hp[1], h2v = hp[2], h3v = hp[3], h4v = hp[4];
    acc[0]  = fmaf(h0.x, w, acc[0]);  acc[1]  = fmaf(h0.y, w, acc[1]);
    acc[2]  = fmaf(h0.z, w, acc[2]);  acc[3]  = fmaf(h0.w, w, acc[3]);
    acc[4]  = fmaf(h1v.x, w, acc[4]); acc[5]  = fmaf(h1v.y, w, acc[5]);
    acc[6]  = fmaf(h1v.z, w, acc[6]); acc[7]  = fmaf(h1v.w, w, acc[7]);
    acc[8]  = fmaf(h2v.x, w, acc[8]); acc[9]  = fmaf(h2v.y, w, acc[9]);
    acc[10] = fmaf(h2v.z, w, acc[10]); acc[11] = fmaf(h2v.w, w, acc[11]);
    acc[12] = fmaf(h3v.x, w, acc[12]); acc[13] = fmaf(h3v.y, w, acc[13]);
    acc[14] = fmaf(h3v.z, w, acc[14]); acc[15] = fmaf(h3v.w, w, acc[15]);
    acc[16] = fmaf(h4v.x, w, acc[16]); acc[17] = fmaf(h4v.y, w, acc[17]);
    acc[18] = fmaf(h4v.z, w, acc[18]); acc[19] = fmaf(h4v.w, w, acc[19]);
  }
  float g = acc[0];
#pragma unroll
  for (int n = 1; n < 20; ++n) g = fmaxf(g, acc[n]);
  gmaxout[(size_t)p*256 + c] = f2bf(g);
#pragma unroll
  for (int n = 0; n < 20; ++n)
    h2out[(size_t)(p*20 + n)*256 + c] = f2bf(acc[n]);
}

// ============================================================
// K5: MFMA GEMM: h3 = [gmax | h2] @ W3 + b3 (163840x512x512), bf16 MFMA.
// Tile 128M x 128N, 4 waves (2m x 2n), each wave 64x64 = 4x4 16x16 frags.
// ============================================================
__global__ __launch_bounds__(256) void gemm3_kernel(const unsigned short* __restrict__ h2,
                                                    const unsigned short* __restrict__ gmax,
                                                    const unsigned short* __restrict__ W3T,
                                                    const float* __restrict__ b3,
                                                    unsigned short* __restrict__ h3,
                                                    float* __restrict__ s3buck) {
  int bid = blockIdx.x;               // 1280 m * 4 n
  int bn = bid & 3, bm = bid >> 2;
  int m0 = bm << 7, n0 = bn << 7;
  int tid = threadIdx.x;
  int lane = tid & 63, w = tid >> 6;
  int mw = w >> 1, nw = w & 1;
  int lr = lane & 15, lg = lane >> 4;
  __shared__ __align__(16) unsigned short As[128][32];
  __shared__ __align__(16) unsigned short Bs[128][32];
  __shared__ float ssum[128], ssq[128];
  f32x4 acc[4][4] = {};

  for (int kc = 0; kc < 512; kc += 32) {
#pragma unroll
    for (int l = 0; l < 2; ++l) {
      int id = tid + (l << 8);        // 0..511 : 128 rows x 4 kgroups
      int row = id >> 2, kg = id & 3;
      int grow = m0 + row;
      const unsigned short* src;
      if (kc < 256) {
        unsigned int pp = (unsigned int)grow / 20u;
        src = gmax + (size_t)pp*256 + kc + (kg << 3);
      } else {
        src = h2 + (size_t)grow*256 + (kc - 256) + (kg << 3);
      }
      *(uint4*)&As[row][kg << 3] = *(const uint4*)src;
    }
#pragma unroll
    for (int l = 0; l < 2; ++l) {
      int id = tid + (l << 8);
      int row = id >> 2, kg = id & 3;
      *(uint4*)&Bs[row][kg << 3] =
          *(const uint4*)(W3T + (size_t)(n0 + row)*512 + kc + (kg << 3));
    }
    __syncthreads();
    bf16x8 a[4], b[4];
#pragma unroll
    for (int t = 0; t < 4; ++t)
      a[t] = *(const bf16x8*)&As[mw*64 + t*16 + lr][lg << 3];
#pragma unroll
    for (int t = 0; t < 4; ++t)
      b[t] = *(const bf16x8*)&Bs[nw*64 + t*16 + lr][lg << 3];
#pragma unroll
    for (int i = 0; i < 4; ++i)
#pragma unroll
      for (int j = 0; j < 4; ++j)
        acc[i][j] = __builtin_amdgcn_mfma_f32_16x16x32_bf16(a[i], b[j], acc[i][j], 0, 0, 0);
    __syncthreads();
  }

  // epilogue: +b3, bf16 store, fused BN3 stats
  if (tid < 128) { ssum[tid] = 0.f; ssq[tid] = 0.f; }
  __syncthreads();
#pragma unroll
  for (int j = 0; j < 4; ++j) {
    int colL = nw*64 + j*16 + lr;     // col within block tile
    int col = n0 + colL;
    float b3v = b3[col];
    float sumv = 0.f, sqv = 0.f;
#pragma unroll
    for (int i = 0; i < 4; ++i) {
      int rbase = m0 + mw*64 + i*16 + lg*4;
#pragma unroll
      for (int r = 0; r < 4; ++r) {
        float v = acc[i][j][r] + b3v;
        h3[(size_t)(rbase + r)*512 + col] = f2bf(v);
        sumv += v; sqv = fmaf(v, v, sqv);
      }
    }
    sumv += __shfl_xor(sumv, 16); sumv += __shfl_xor(sumv, 32);
    sqv  += __shfl_xor(sqv, 16);  sqv  += __shfl_xor(sqv, 32);
    if (lg == 0) {
      atomicAdd(&ssum[colL], sumv);
      atomicAdd(&ssq[colL], sqv);
    }
  }
  __syncthreads();
  if (tid < 128) {
    int bkt = (bid & 63) * 1024;
    atomicAdd(&s3buck[bkt + n0 + tid], ssum[tid]);
    atomicAdd(&s3buck[bkt + 512 + n0 + tid], ssq[tid]);
  }
}

__global__ void bn_prep3(const float* __restrict__ g3, const float* __restrict__ be3,
                         const float* __restrict__ s3buck, float* __restrict__ misc) {
  int c = threadIdx.x;  // 512
  float s = 0.f, q = 0.f;
  for (int b = 0; b < 64; ++b) { s += s3buck[b*1024 + c]; q += s3buck[b*1024 + 512 + c]; }
  const float inv = 1.0f / (float)NSAMP;
  float mu = s * inv;
  float var = q * inv - mu * mu;
  float a = g3[c] / sqrtf(var + 1e-5f);
  misc[256 + c] = a;
  misc[768 + c] = be3[c] - mu * a;
}

// ============================================================
// K7: MFMA GEMM: h4 = relu(a3*h3+d3) @ W4 (+b4) with FUSED max-pool over
// K=20. M-tile 160 (8 points), N-tile 128, 4 waves (2m x 2n).
// ============================================================
__global__ __launch_bounds__(256) void gemm4_kernel(const unsigned short* __restrict__ h3,
                                                    const unsigned short* __restrict__ W4T,
                                                    const float* __restrict__ b4,
                                                    const float* __restrict__ misc,
                                                    float* __restrict__ outf) {
  int bid = blockIdx.x;             // 1024 m * 3 n
  int bm = bid / 3, bn = bid - bm*3;
  int m0 = bm * 160, n0 = bn << 7;
  int tid = threadIdx.x;
  int lane = tid & 63, w = tid >> 6;
  int mw = w >> 1, nw = w & 1;
  int lr = lane & 15, lg = lane >> 4;
  __shared__ __align__(16) unsigned short As[160][32];
  __shared__ __align__(16) unsigned short Bs[128][32];
  __shared__ float af[512], df[512];
  __shared__ float pool[40][132];   // padded stride (bank spread)
#pragma unroll
  for (int l = 0; l < 2; ++l) {
    int id = tid + (l << 8);
    af[id] = misc[256 + id];
    df[id] = misc[768 + id];
  }
  __syncthreads();
  f32x4 acc[5][4] = {};

  for (int kc = 0; kc < 512; kc += 32) {
#pragma unroll
    for (int l = 0; l < 3; ++l) {
      int id = tid + (l << 8);
      if (id < 640) {                 // 160 rows x 4 kgroups
        int row = id >> 2, kg = id & 3;
        uint4 v = *(const uint4*)(h3 + (size_t)(m0 + row)*512 + kc + (kg << 3));
        int kb = kc + (kg << 3);
        unsigned int o[4];
#pragma unroll
        for (int q = 0; q < 4; ++q) {
          unsigned int u = ((const unsigned int*)&v)[q];
          float lo = bf2f((unsigned short)(u & 0xffffu));
          float hi = bf2f((unsigned short)(u >> 16));
          int k0 = kb + q*2;
          lo = fmaxf(fmaf(af[k0],   lo, df[k0]),   0.f);
          hi = fmaxf(fmaf(af[k0+1], hi, df[k0+1]), 0.f);
          o[q] = (unsigned int)f2bf(lo) | ((unsigned int)f2bf(hi) << 16);
        }
        *(uint4*)&As[row][kg << 3] = *(const uint4*)o;
      }
    }
#pragma unroll
    for (int l = 0; l < 2; ++l) {
      int id = tid + (l << 8);
      int row = id >> 2, kg = id & 3;
      *(uint4*)&Bs[row][kg << 3] =
          *(const uint4*)(W4T + (size_t)(n0 + row)*512 + kc + (kg << 3));
    }
    __syncthreads();
    bf16x8 a[5], b[4];
#pragma unroll
    for (int t = 0; t < 5; ++t)
      a[t] = *(const bf16x8*)&As[mw*80 + t*16 + lr][lg << 3];
#pragma unroll
    for (int t = 0; t < 4; ++t)
      b[t] = *(const bf16x8*)&Bs[nw*64 + t*16 + lr][lg << 3];
#pragma unroll
    for (int i = 0; i < 5; ++i)
#pragma unroll
      for (int j = 0; j < 4; ++j)
        acc[i][j] = __builtin_amdgcn_mfma_f32_16x16x32_bf16(a[i], b[j], acc[i][j], 0, 0, 0);
    __syncthreads();
  }

  // fused max-pool: per-lane reg-max (4 rows, point-pure) -> LDS -> pool
#pragma unroll
  for (int i = 0; i < 5; ++i)
#pragma unroll
    for (int j = 0; j < 4; ++j) {
      float m = fmaxf(fmaxf(acc[i][j][0], acc[i][j][1]),
                      fmaxf(acc[i][j][2], acc[i][j][3]));
      pool[mw*20 + i*4 + lg][nw*64 + j*16 + lr] = m;
    }
  __syncthreads();
#pragma unroll
  for (int l = 0; l < 4; ++l) {
    int id = tid + (l << 8);          // 0..1023 : 8 points x 128 cols
    int q = id >> 7, c = id & 127;
    int mwq = q >> 2, ql = q & 3;
    float v = pool[mwq*20 + ql*5][c];
#pragma unroll
    for (int u = 1; u < 5; ++u) v = fmaxf(v, pool[mwq*20 + ql*5 + u][c]);
    outf[(size_t)(bm*8 + q)*384 + n0 + c] = v + b4[n0 + c];
  }
}

// ============================================================
// Workspace layout:
//   0x0000000  idx        640 KB
//   0x00A0000  misc       1280 f32
//   0x00A2000  s1buck     32 KB   (zeroed)
//   0x00AA000  s3buck     256 KB  (zeroed)
//   0x00F0000  W3T bf16   512 KB
//   0x0170000  W4T bf16   384 KB
//   0x0200000  gmax bf16  4 MB
//   0x0600000  h2   bf16  80 MB
//   0x5600000  h3   bf16  160 MB  -> end 0xF600000
// ============================================================
extern "C" void kernel_launch(void* const* d_in, const int* in_sizes, int n_in,
                              void* d_out, int out_size, void* d_ws, size_t ws_size,
                              hipStream_t stream) {
  const float* xyz = (const float*)d_in[0];
  const float* W1  = (const float*)d_in[1];
  const float* b1  = (const float*)d_in[2];
  const float* g1  = (const float*)d_in[3];
  const float* be1 = (const float*)d_in[4];
  const float* W2  = (const float*)d_in[5];
  const float* b2  = (const float*)d_in[6];
  const float* W3  = (const float*)d_in[7];
  const float* b3  = (const float*)d_in[8];
  const float* g3  = (const float*)d_in[9];
  const float* be3 = (const float*)d_in[10];
  const float* W4  = (const float*)d_in[11];
  const float* b4  = (const float*)d_in[12];

  char* ws = (char*)d_ws;
  int*            idx    = (int*)ws;
  float*          misc   = (float*)(ws + 0xA0000);
  float*          s1buck = (float*)(ws + 0xA2000);
  float*          s3buck = (float*)(ws + 0xAA000);
  unsigned short* W3T    = (unsigned short*)(ws + 0xF0000);
  unsigned short* W4T    = (unsigned short*)(ws + 0x170000);
  unsigned short* gmax   = (unsigned short*)(ws + 0x200000);
  unsigned short* h2     = (unsigned short*)(ws + 0x600000);
  unsigned short* h3     = (unsigned short*)(ws + 0x5600000ULL);

  float* ofp   = (float*)d_out;
  float* oxyz  = ofp;             // 24576 fp32
  float* ofeat = ofp + 24576;     // 8192*384 fp32

  hipMemsetAsync(ws + 0xA2000, 0, 0x48000, stream);   // zero stat buckets

  wprep_kernel<<<(512*512 + 384*512)/256, 256, 0, stream>>>(W3, W4, W3T, W4T);
  knn_kernel<<<NPTS, 256, 0, stream>>>(xyz, idx, oxyz);
  h1_stats_kernel<<<NSAMP/512, 256, 0, stream>>>(xyz, idx, W1, b1, s1buck);
  bn_prep1<<<1, 128, 0, stream>>>(g1, be1, s1buck, misc);
  h2_kernel<<<NPTS, 256, 0, stream>>>(xyz, idx, W1, b1, W2, b2, misc, h2, gmax);
  gemm3_kernel<<<(NSAMP/128)*4, 256, 0, stream>>>(h2, gmax, W3T, b3, h3, s3buck);
  bn_prep3<<<1, 512, 0, stream>>>(g3, be3, s3buck, misc);
  gemm4_kernel<<<(NPTS/8)*3, 256, 0, stream>>>(h3, W4T, b4, misc, ofeat);
}

// Round 6
// 584.041 us; speedup vs baseline: 4.0892x; 1.2142x over previous
//
#include <hip/hip_runtime.h>
#include <float.h>

// Problem constants: B=2, N=4096, K=20, H=384
// Inputs: fp32 arrays (values bf16-quantized by harness). Output: fp32.
#define NPTS_B 4096
#define NPTS 8192            // B*N
#define KNN 20
#define NSAMP (NPTS*KNN)     // 163840

typedef __attribute__((ext_vector_type(8))) short bf16x8;
typedef __attribute__((ext_vector_type(4))) float f32x4;

// -------- bf16 helpers (internal staging only) --------
static __device__ __forceinline__ float bf2f(unsigned short u) {
  return __uint_as_float(((unsigned int)u) << 16);
}
static __device__ __forceinline__ unsigned short f2bf(float f) {
  unsigned int u = __float_as_uint(f);
  u += 0x7fffu + ((u >> 16) & 1u);
  return (unsigned short)(u >> 16);
}
static __device__ __forceinline__ unsigned long long u64min(unsigned long long a,
                                                           unsigned long long b) {
  return a < b ? a : b;
}
static __device__ __forceinline__ unsigned long long shflx64(unsigned long long v, int m) {
  int lo = __shfl_xor((int)(unsigned int)(v & 0xffffffffull), m);
  int hi = __shfl_xor((int)(unsigned int)(v >> 32), m);
  return ((unsigned long long)(unsigned int)hi << 32) | (unsigned int)lo;
}

// ============================================================
// K0: weight prep — W3 -> W3T bf16 [n][k]; W4 -> W4T bf16 [n][k];
// W2 (128x256) -> W2T bf16 [n=256][k=128]. All values bf16-grid -> EXACT.
// ============================================================
__global__ __launch_bounds__(256) void wprep_kernel(const float* __restrict__ W3,
                                                    const float* __restrict__ W4,
                                                    const float* __restrict__ W2,
                                                    unsigned short* __restrict__ W3T,
                                                    unsigned short* __restrict__ W4T,
                                                    unsigned short* __restrict__ W2T) {
  int id = blockIdx.x * 256 + threadIdx.x;
  if (id < 512*512) {
    int n = id >> 9, k = id & 511;
    W3T[id] = f2bf(W3[k*512 + n]);
  } else if (id < 512*512 + 384*512) {
    int id2 = id - 512*512;
    int n = id2 >> 9, k = id2 & 511;
    W4T[id2] = f2bf(W4[k*384 + n]);
  } else {
    int id2 = id - (512*512 + 384*512);   // < 256*128
    int n = id2 >> 7, k = id2 & 127;
    W2T[id2] = f2bf(W2[k*256 + n]);
  }
}

// ============================================================
// K1: KNN (one block per point). u64-packed (d2_bits<<32|j) extract-min,
// incremental cached minima, one barrier per round.
// ============================================================
__global__ __launch_bounds__(256) void knn_kernel(const float* __restrict__ xyz,
                                                  int* __restrict__ idx,
                                                  float* __restrict__ out_xyz) {
#pragma clang fp contract(off)
  int p = blockIdx.x;            // 0..8191
  int base = p & ~4095;          // batch base row
  int tid = threadIdx.x;
  int wv = tid >> 6;
  int ln = tid & 63;
  const float* xb = xyz + (size_t)base * 3;
  float xi0 = xyz[p*3+0], xi1 = xyz[p*3+1], xi2 = xyz[p*3+2];
  float sqi = (xi0*xi0 + xi1*xi1) + xi2*xi2;

  unsigned long long cand[16];
#pragma unroll
  for (int u = 0; u < 16; ++u) {
    int j = tid + (u << 8);
    float a0 = xb[j*3+0], a1 = xb[j*3+1], a2 = xb[j*3+2];
    float sqj = (a0*a0 + a1*a1) + a2*a2;
    float dt  = (xi0*a0 + xi1*a1) + xi2*a2;
    float d2  = (sqi + sqj) - 2.0f*dt;
    cand[u] = ((unsigned long long)__float_as_uint(d2) << 32) | (unsigned int)j;
  }
  unsigned long long myloc;
  {
    unsigned long long t[8];
#pragma unroll
    for (int u = 0; u < 8; ++u) t[u] = u64min(cand[u], cand[u + 8]);
#pragma unroll
    for (int u = 0; u < 4; ++u) t[u] = u64min(t[u], t[u + 4]);
    t[0] = u64min(t[0], t[2]); t[1] = u64min(t[1], t[3]);
    myloc = u64min(t[0], t[1]);
  }
  unsigned long long wmreg = myloc;
#pragma unroll
  for (int off = 1; off < 64; off <<= 1) wmreg = u64min(wmreg, shflx64(wmreg, off));

  __shared__ __align__(16) unsigned long long wbuf[2][4];
  __shared__ int outbuf[20];
  if (ln == 0) wbuf[0][wv] = wmreg;
  __syncthreads();

  for (int r = 0; r < 20; ++r) {
    int cur = r & 1;
    unsigned long long w0 = wbuf[cur][0], w1 = wbuf[cur][1];
    unsigned long long w2 = wbuf[cur][2], w3 = wbuf[cur][3];
    unsigned long long g = u64min(u64min(w0, w1), u64min(w2, w3));
    int wj = (int)(unsigned int)(g & 0xffffffffu);
    if (tid == (wj & 255)) {
      outbuf[r] = base + wj;
      unsigned long long m = ~0ull;
#pragma unroll
      for (int u = 0; u < 16; ++u) {
        if (cand[u] == g) cand[u] = ~0ull;
        m = u64min(m, cand[u]);
      }
      myloc = m;
    }
    if (wv == ((wj >> 6) & 3)) {
      unsigned long long t = myloc;
#pragma unroll
      for (int off = 1; off < 64; off <<= 1) t = u64min(t, shflx64(t, off));
      wmreg = t;
    }
    if (ln == 0) wbuf[cur ^ 1][wv] = wmreg;
    __syncthreads();
  }
  if (tid < 20) idx[p*20 + tid] = outbuf[tid];
  if (tid < 3) out_xyz[p*3 + tid] = xyz[p*3 + tid];   // exact fp32 copy
}

// ============================================================
// K2: BN1 statistics — recompute h1 = e@W1 + b1 per sample,
// accumulate per-channel sum / sumsq into 32 buckets.
// ============================================================
__global__ __launch_bounds__(256) void h1_stats_kernel(const float* __restrict__ xyz,
                                                       const int* __restrict__ idx,
                                                       const float* __restrict__ W1,
                                                       const float* __restrict__ b1,
                                                       float* __restrict__ s1buck) {
  int blk = blockIdx.x;         // 320 blocks * 512 samples
  int tid = threadIdx.x;
  int c = tid & 127, half = tid >> 7;
  float w[6];
#pragma unroll
  for (int d = 0; d < 6; ++d) w[d] = W1[d*128 + c];
  float bb = b1[c];
  float sum = 0.f, sq = 0.f;
  int s0 = blk * 512;
  for (int u = 0; u < 256; ++u) {
    int s = s0 + (u << 1) + half;
    unsigned int p = (unsigned int)s / 20u;
    int jg = idx[s];
    float xi0 = xyz[p*3+0], xi1 = xyz[p*3+1], xi2 = xyz[p*3+2];
    float e0 = xyz[jg*3+0] - xi0;
    float e1 = xyz[jg*3+1] - xi1;
    float e2 = xyz[jg*3+2] - xi2;
    float h = bb;
    h = fmaf(e0, w[0], h); h = fmaf(e1, w[1], h); h = fmaf(e2, w[2], h);
    h = fmaf(xi0, w[3], h); h = fmaf(xi1, w[4], h); h = fmaf(xi2, w[5], h);
    sum += h; sq = fmaf(h, h, sq);
  }
  __shared__ float ls[128], lq[128];
  if (!half) { ls[c] = sum; lq[c] = sq; }
  __syncthreads();
  if (half) {
    int bkt = (blk & 31) * 256;
    atomicAdd(&s1buck[bkt + c], ls[c] + sum);
    atomicAdd(&s1buck[bkt + 128 + c], lq[c] + sq);
  }
}

__global__ void bn_prep1(const float* __restrict__ g1, const float* __restrict__ be1,
                         const float* __restrict__ s1buck, float* __restrict__ misc) {
  int c = threadIdx.x;  // 128
  float s = 0.f, q = 0.f;
  for (int b = 0; b < 32; ++b) { s += s1buck[b*256 + c]; q += s1buck[b*256 + 128 + c]; }
  const float inv = 1.0f / (float)NSAMP;
  float mu = s * inv;
  float var = q * inv - mu * mu;
  float a = g1[c] / sqrtf(var + 1e-5f);
  misc[c] = a;
  misc[128 + c] = be1[c] - mu * a;
}

// ============================================================
// K4: MFMA h2: per block of 4 points (M=80): edge -> h1 (BN1+ReLU, bf16
// into LDS A-tile) -> h2 = h1 @ W2T via MFMA (N=256, K=128) -> +b2 ->
// h2 bf16 store + fused per-point gmax (point-pure 4-row reg groups).
// B-fragments preloaded to registers from W2T (L2-hot, no LDS staging).
// ============================================================
__global__ __launch_bounds__(256) void h2_kernel(const float* __restrict__ xyz,
                                                 const int* __restrict__ idx,
                                                 const float* __restrict__ W1,
                                                 const float* __restrict__ b1,
                                                 const unsigned short* __restrict__ W2T,
                                                 const float* __restrict__ b2,
                                                 const float* __restrict__ misc,
                                                 unsigned short* __restrict__ h2out,
                                                 unsigned short* __restrict__ gmaxout) {
  int p0 = blockIdx.x << 2;          // 4 points
  int tid = threadIdx.x;
  int w = tid >> 6, lane = tid & 63;
  int lr = lane & 15, lg = lane >> 4;
  __shared__ float e[80][6];
  __shared__ __align__(16) unsigned short As[80][136];  // pad: 2-way-free banks
  __shared__ float pool[20][264];

  // B preload: 16 frags/wave straight to registers (in flight during phases)
  bf16x8 bfr[4][4];
#pragma unroll
  for (int j = 0; j < 4; ++j)
#pragma unroll
    for (int kk = 0; kk < 4; ++kk)
      bfr[j][kk] = *(const bf16x8*)(W2T + (size_t)(w*64 + j*16 + lr)*128 + kk*32 + lg*8);

  // edge phase
  if (tid < 80) {
    int pl = (unsigned int)tid / 20u;
    int p = p0 + pl;
    int jg = idx[p0*20 + tid];
    float xi0 = xyz[p*3+0], xi1 = xyz[p*3+1], xi2 = xyz[p*3+2];
    e[tid][0] = xyz[jg*3+0] - xi0;
    e[tid][1] = xyz[jg*3+1] - xi1;
    e[tid][2] = xyz[jg*3+2] - xi2;
    e[tid][3] = xi0; e[tid][4] = xi1; e[tid][5] = xi2;
  }
  __syncthreads();

  // h1 phase: cell (row, c); thread's c fixed -> W1 col cached
  {
    int c = tid & 127, half = tid >> 7;
    float w1v[6];
#pragma unroll
    for (int d = 0; d < 6; ++d) w1v[d] = W1[d*128 + c];
    float b1v = b1[c], a1 = misc[c], d1 = misc[128 + c];
#pragma unroll
    for (int u = 0; u < 40; ++u) {
      int row = (u << 1) | half;
      float v = b1v;
#pragma unroll
      for (int d = 0; d < 6; ++d) v = fmaf(e[row][d], w1v[d], v);
      v = fmaxf(fmaf(a1, v, d1), 0.f);
      As[row][c] = f2bf(v);
    }
  }
  __syncthreads();

  // MFMA: wave w -> cols w*64..+63, all 80 rows (5 m-frags), K=128
  f32x4 acc[5][4] = {};
#pragma unroll
  for (int kk = 0; kk < 4; ++kk) {
    bf16x8 a[5];
#pragma unroll
    for (int i = 0; i < 5; ++i)
      a[i] = *(const bf16x8*)&As[i*16 + lr][kk*32 + lg*8];
#pragma unroll
    for (int i = 0; i < 5; ++i)
#pragma unroll
      for (int j = 0; j < 4; ++j)
        acc[i][j] = __builtin_amdgcn_mfma_f32_16x16x32_bf16(a[i], bfr[j][kk], acc[i][j], 0, 0, 0);
  }

  // epilogue: +b2, h2 bf16 store, point-pure reg-max -> pool
  float b2v[4];
#pragma unroll
  for (int j = 0; j < 4; ++j) b2v[j] = b2[w*64 + j*16 + lr];
#pragma unroll
  for (int i = 0; i < 5; ++i) {
    int rbase = p0*20 + i*16 + lg*4;
#pragma unroll
    for (int j = 0; j < 4; ++j) {
      int col = w*64 + j*16 + lr;
      float v0 = acc[i][j][0] + b2v[j];
      float v1 = acc[i][j][1] + b2v[j];
      float v2 = acc[i][j][2] + b2v[j];
      float v3 = acc[i][j][3] + b2v[j];
      h2out[(size_t)(rbase+0)*256 + col] = f2bf(v0);
      h2out[(size_t)(rbase+1)*256 + col] = f2bf(v1);
      h2out[(size_t)(rbase+2)*256 + col] = f2bf(v2);
      h2out[(size_t)(rbase+3)*256 + col] = f2bf(v3);
      pool[i*4 + lg][col] = fmaxf(fmaxf(v0, v1), fmaxf(v2, v3));
    }
  }
  __syncthreads();
#pragma unroll
  for (int l = 0; l < 4; ++l) {
    int id = tid + (l << 8);        // 0..1023 : 4 points x 256 cols
    int q = id >> 8, col = id & 255;
    float v = pool[q*5][col];
#pragma unroll
    for (int u = 1; u < 5; ++u) v = fmaxf(v, pool[q*5 + u][col]);
    gmaxout[(size_t)(p0 + q)*256 + col] = f2bf(v);
  }
}

// ============================================================
// K5: MFMA GEMM: h3 = [gmax | h2] @ W3 + b3 (163840x512x512), bf16 MFMA.
// Tile 128M x 128N, 4 waves (2m x 2n), each wave 64x64 = 4x4 16x16 frags.
// ============================================================
__global__ __launch_bounds__(256) void gemm3_kernel(const unsigned short* __restrict__ h2,
                                                    const unsigned short* __restrict__ gmax,
                                                    const unsigned short* __restrict__ W3T,
                                                    const float* __restrict__ b3,
                                                    unsigned short* __restrict__ h3,
                                                    float* __restrict__ s3buck) {
  int bid = blockIdx.x;               // 1280 m * 4 n
  int bn = bid & 3, bm = bid >> 2;
  int m0 = bm << 7, n0 = bn << 7;
  int tid = threadIdx.x;
  int lane = tid & 63, w = tid >> 6;
  int mw = w >> 1, nw = w & 1;
  int lr = lane & 15, lg = lane >> 4;
  __shared__ __align__(16) unsigned short As[128][32];
  __shared__ __align__(16) unsigned short Bs[128][32];
  __shared__ float ssum[128], ssq[128];
  f32x4 acc[4][4] = {};

  for (int kc = 0; kc < 512; kc += 32) {
#pragma unroll
    for (int l = 0; l < 2; ++l) {
      int id = tid + (l << 8);        // 0..511 : 128 rows x 4 kgroups
      int row = id >> 2, kg = id & 3;
      int grow = m0 + row;
      const unsigned short* src;
      if (kc < 256) {
        unsigned int pp = (unsigned int)grow / 20u;
        src = gmax + (size_t)pp*256 + kc + (kg << 3);
      } else {
        src = h2 + (size_t)grow*256 + (kc - 256) + (kg << 3);
      }
      *(uint4*)&As[row][kg << 3] = *(const uint4*)src;
    }
#pragma unroll
    for (int l = 0; l < 2; ++l) {
      int id = tid + (l << 8);
      int row = id >> 2, kg = id & 3;
      *(uint4*)&Bs[row][kg << 3] =
          *(const uint4*)(W3T + (size_t)(n0 + row)*512 + kc + (kg << 3));
    }
    __syncthreads();
    bf16x8 a[4], b[4];
#pragma unroll
    for (int t = 0; t < 4; ++t)
      a[t] = *(const bf16x8*)&As[mw*64 + t*16 + lr][lg << 3];
#pragma unroll
    for (int t = 0; t < 4; ++t)
      b[t] = *(const bf16x8*)&Bs[nw*64 + t*16 + lr][lg << 3];
#pragma unroll
    for (int i = 0; i < 4; ++i)
#pragma unroll
      for (int j = 0; j < 4; ++j)
        acc[i][j] = __builtin_amdgcn_mfma_f32_16x16x32_bf16(a[i], b[j], acc[i][j], 0, 0, 0);
    __syncthreads();
  }

  // epilogue: +b3, bf16 store, fused BN3 stats
  if (tid < 128) { ssum[tid] = 0.f; ssq[tid] = 0.f; }
  __syncthreads();
#pragma unroll
  for (int j = 0; j < 4; ++j) {
    int colL = nw*64 + j*16 + lr;     // col within block tile
    int col = n0 + colL;
    float b3v = b3[col];
    float sumv = 0.f, sqv = 0.f;
#pragma unroll
    for (int i = 0; i < 4; ++i) {
      int rbase = m0 + mw*64 + i*16 + lg*4;
#pragma unroll
      for (int r = 0; r < 4; ++r) {
        float v = acc[i][j][r] + b3v;
        h3[(size_t)(rbase + r)*512 + col] = f2bf(v);
        sumv += v; sqv = fmaf(v, v, sqv);
      }
    }
    sumv += __shfl_xor(sumv, 16); sumv += __shfl_xor(sumv, 32);
    sqv  += __shfl_xor(sqv, 16);  sqv  += __shfl_xor(sqv, 32);
    if (lg == 0) {
      atomicAdd(&ssum[colL], sumv);
      atomicAdd(&ssq[colL], sqv);
    }
  }
  __syncthreads();
  if (tid < 128) {
    int bkt = (bid & 63) * 1024;
    atomicAdd(&s3buck[bkt + n0 + tid], ssum[tid]);
    atomicAdd(&s3buck[bkt + 512 + n0 + tid], ssq[tid]);
  }
}

__global__ void bn_prep3(const float* __restrict__ g3, const float* __restrict__ be3,
                         const float* __restrict__ s3buck, float* __restrict__ misc) {
  int c = threadIdx.x;  // 512
  float s = 0.f, q = 0.f;
  for (int b = 0; b < 64; ++b) { s += s3buck[b*1024 + c]; q += s3buck[b*1024 + 512 + c]; }
  const float inv = 1.0f / (float)NSAMP;
  float mu = s * inv;
  float var = q * inv - mu * mu;
  float a = g3[c] / sqrtf(var + 1e-5f);
  misc[256 + c] = a;
  misc[768 + c] = be3[c] - mu * a;
}

// ============================================================
// K7: MFMA GEMM: h4 = relu(a3*h3+d3) @ W4 (+b4) with FUSED max-pool over
// K=20. M-tile 160 (8 points), N-tile 128, 4 waves (2m x 2n).
// ============================================================
__global__ __launch_bounds__(256) void gemm4_kernel(const unsigned short* __restrict__ h3,
                                                    const unsigned short* __restrict__ W4T,
                                                    const float* __restrict__ b4,
                                                    const float* __restrict__ misc,
                                                    float* __restrict__ outf) {
  int bid = blockIdx.x;             // 1024 m * 3 n
  int bm = bid / 3, bn = bid - bm*3;
  int m0 = bm * 160, n0 = bn << 7;
  int tid = threadIdx.x;
  int lane = tid & 63, w = tid >> 6;
  int mw = w >> 1, nw = w & 1;
  int lr = lane & 15, lg = lane >> 4;
  __shared__ __align__(16) unsigned short As[160][32];
  __shared__ __align__(16) unsigned short Bs[128][32];
  __shared__ float af[512], df[512];
  __shared__ float pool[40][132];   // padded stride (bank spread)
#pragma unroll
  for (int l = 0; l < 2; ++l) {
    int id = tid + (l << 8);
    af[id] = misc[256 + id];
    df[id] = misc[768 + id];
  }
  __syncthreads();
  f32x4 acc[5][4] = {};

  for (int kc = 0; kc < 512; kc += 32) {
#pragma unroll
    for (int l = 0; l < 3; ++l) {
      int id = tid + (l << 8);
      if (id < 640) {                 // 160 rows x 4 kgroups
        int row = id >> 2, kg = id & 3;
        uint4 v = *(const uint4*)(h3 + (size_t)(m0 + row)*512 + kc + (kg << 3));
        int kb = kc + (kg << 3);
        unsigned int o[4];
#pragma unroll
        for (int q = 0; q < 4; ++q) {
          unsigned int u = ((const unsigned int*)&v)[q];
          float lo = bf2f((unsigned short)(u & 0xffffu));
          float hi = bf2f((unsigned short)(u >> 16));
          int k0 = kb + q*2;
          lo = fmaxf(fmaf(af[k0],   lo, df[k0]),   0.f);
          hi = fmaxf(fmaf(af[k0+1], hi, df[k0+1]), 0.f);
          o[q] = (unsigned int)f2bf(lo) | ((unsigned int)f2bf(hi) << 16);
        }
        *(uint4*)&As[row][kg << 3] = *(const uint4*)o;
      }
    }
#pragma unroll
    for (int l = 0; l < 2; ++l) {
      int id = tid + (l << 8);
      int row = id >> 2, kg = id & 3;
      *(uint4*)&Bs[row][kg << 3] =
          *(const uint4*)(W4T + (size_t)(n0 + row)*512 + kc + (kg << 3));
    }
    __syncthreads();
    bf16x8 a[5], b[4];
#pragma unroll
    for (int t = 0; t < 5; ++t)
      a[t] = *(const bf16x8*)&As[mw*80 + t*16 + lr][lg << 3];
#pragma unroll
    for (int t = 0; t < 4; ++t)
      b[t] = *(const bf16x8*)&Bs[nw*64 + t*16 + lr][lg << 3];
#pragma unroll
    for (int i = 0; i < 5; ++i)
#pragma unroll
      for (int j = 0; j < 4; ++j)
        acc[i][j] = __builtin_amdgcn_mfma_f32_16x16x32_bf16(a[i], b[j], acc[i][j], 0, 0, 0);
    __syncthreads();
  }

  // fused max-pool: per-lane reg-max (4 rows, point-pure) -> LDS -> pool
#pragma unroll
  for (int i = 0; i < 5; ++i)
#pragma unroll
    for (int j = 0; j < 4; ++j) {
      float m = fmaxf(fmaxf(acc[i][j][0], acc[i][j][1]),
                      fmaxf(acc[i][j][2], acc[i][j][3]));
      pool[mw*20 + i*4 + lg][nw*64 + j*16 + lr] = m;
    }
  __syncthreads();
#pragma unroll
  for (int l = 0; l < 4; ++l) {
    int id = tid + (l << 8);          // 0..1023 : 8 points x 128 cols
    int q = id >> 7, c = id & 127;
    int mwq = q >> 2, ql = q & 3;
    float v = pool[mwq*20 + ql*5][c];
#pragma unroll
    for (int u = 1; u < 5; ++u) v = fmaxf(v, pool[mwq*20 + ql*5 + u][c]);
    outf[(size_t)(bm*8 + q)*384 + n0 + c] = v + b4[n0 + c];
  }
}

// ============================================================
// Workspace layout:
//   0x0000000  idx        640 KB
//   0x00A0000  misc       1280 f32
//   0x00A2000  s1buck     32 KB   (zeroed)
//   0x00AA000  s3buck     256 KB  (zeroed)
//   0x00F0000  W3T bf16   512 KB
//   0x0170000  W4T bf16   384 KB
//   0x01D0000  W2T bf16   64 KB
//   0x0200000  gmax bf16  4 MB
//   0x0600000  h2   bf16  80 MB
//   0x5600000  h3   bf16  160 MB  -> end 0xF600000
// ============================================================
extern "C" void kernel_launch(void* const* d_in, const int* in_sizes, int n_in,
                              void* d_out, int out_size, void* d_ws, size_t ws_size,
                              hipStream_t stream) {
  const float* xyz = (const float*)d_in[0];
  const float* W1  = (const float*)d_in[1];
  const float* b1  = (const float*)d_in[2];
  const float* g1  = (const float*)d_in[3];
  const float* be1 = (const float*)d_in[4];
  const float* W2  = (const float*)d_in[5];
  const float* b2  = (const float*)d_in[6];
  const float* W3  = (const float*)d_in[7];
  const float* b3  = (const float*)d_in[8];
  const float* g3  = (const float*)d_in[9];
  const float* be3 = (const float*)d_in[10];
  const float* W4  = (const float*)d_in[11];
  const float* b4  = (const float*)d_in[12];

  char* ws = (char*)d_ws;
  int*            idx    = (int*)ws;
  float*          misc   = (float*)(ws + 0xA0000);
  float*          s1buck = (float*)(ws + 0xA2000);
  float*          s3buck = (float*)(ws + 0xAA000);
  unsigned short* W3T    = (unsigned short*)(ws + 0xF0000);
  unsigned short* W4T    = (unsigned short*)(ws + 0x170000);
  unsigned short* W2T    = (unsigned short*)(ws + 0x1D0000);
  unsigned short* gmax   = (unsigned short*)(ws + 0x200000);
  unsigned short* h2     = (unsigned short*)(ws + 0x600000);
  unsigned short* h3     = (unsigned short*)(ws + 0x5600000ULL);

  float* ofp   = (float*)d_out;
  float* oxyz  = ofp;             // 24576 fp32
  float* ofeat = ofp + 24576;     // 8192*384 fp32

  hipMemsetAsync(ws + 0xA2000, 0, 0x48000, stream);   // zero stat buckets

  wprep_kernel<<<(512*512 + 384*512 + 256*128)/256, 256, 0, stream>>>(W3, W4, W2, W3T, W4T, W2T);
  knn_kernel<<<NPTS, 256, 0, stream>>>(xyz, idx, oxyz);
  h1_stats_kernel<<<NSAMP/512, 256, 0, stream>>>(xyz, idx, W1, b1, s1buck);
  bn_prep1<<<1, 128, 0, stream>>>(g1, be1, s1buck, misc);
  h2_kernel<<<NPTS/4, 256, 0, stream>>>(xyz, idx, W1, b1, W2T, b2, misc, h2, gmax);
  gemm3_kernel<<<(NSAMP/128)*4, 256, 0, stream>>>(h2, gmax, W3T, b3, h3, s3buck);
  bn_prep3<<<1, 512, 0, stream>>>(g3, be3, s3buck, misc);
  gemm4_kernel<<<(NPTS/8)*3, 256, 0, stream>>>(h3, W4T, b4, misc, ofeat);
}